// Round 4
// baseline (4886.392 us; speedup 1.0000x reference)
//
#include <hip/hip_runtime.h>
#include <math.h>

// Problem constants (from setup_inputs): B=4, H=384, W=1280, NUM=8, IDX_REF=4
static constexpr int B_ = 4;
static constexpr int H_ = 384;
static constexpr int W_ = 1280;
static constexpr int HW_ = H_ * W_;

// ---------------------------------------------------------------------------
// conv1 with fused guidance: stages the 12-channel guidance tile
// [normal(3), left(3), right(3), warp(right)-left(3)] directly into LDS
// (computing the warp on the fly), then 3x3 conv + BN + ReLU, CO_TILE=32
// (all output channels, single co-block). Out: x1 band (g,32,out_rows,W).
// __launch_bounds__(256,4): 128-VGPR budget so acc[] stays in arch VGPRs
// (R3 lesson: default budget put acc in AGPRs -> 3x VALU via accvgpr moves).
// ---------------------------------------------------------------------------
__global__ __launch_bounds__(256, 4) void conv1_fused_band(
    const float* __restrict__ disp, const float* __restrict__ normal,
    const float* __restrict__ left, const float* __restrict__ right,
    const float* __restrict__ wgt,
    const float* __restrict__ bn_g, const float* __restrict__ bn_b,
    const float* __restrict__ bn_m, const float* __restrict__ bn_v,
    float* __restrict__ out, int b0, int out_y0, int out_rows)
{
  constexpr int TX = 16, TY = 16;
  constexpr int C_IN = 12, C_OUT = 32;
  constexpr int LH = TY + 2, LW = TX + 2, LWP = LW + 1;

  __shared__ float smem[C_IN][LH][LWP];

  const int tilesX = W_ / TX;
  const int tilesY = (out_rows + TY - 1) / TY;
  int t = blockIdx.x;
  int txi = t % tilesX; t /= tilesX;
  int tyi = t % tilesY;
  int gi  = t / tilesY;
  const int x0  = txi * TX;
  const int oy0 = out_y0 + tyi * TY;
  const int b   = b0 + gi;

  const int tid = threadIdx.x;
  const int lx = tid % TX;
  const int ly = tid / TX;

  // ---- stage guidance tile (computed on the fly) ----
  for (int i = tid; i < C_IN * LH * LW; i += 256) {
    int c = i / (LH * LW);
    int r = i % (LH * LW);
    int yy = r / LW;
    int xx = r % LW;
    int gy = oy0 + yy - 1;
    int gx = x0 + xx - 1;
    float val = 0.f;
    if (gy >= 0 && gy < H_ && gx >= 0 && gx < W_) {
      int p = gy * W_ + gx;
      if (c < 3) {
        val = normal[(size_t)(b * 3 + c) * HW_ + p];
      } else if (c < 6) {
        val = left[(size_t)(b * 3 + c - 3) * HW_ + p];
      } else if (c < 9) {
        val = right[(size_t)(b * 3 + c - 6) * HW_ + p];
      } else {
        int cc = c - 9;
        float d = disp[(size_t)b * HW_ + p];
        float xs = (float)gx - d;
        float x0f = floorf(xs);
        int xi0 = (int)x0f;
        float w1 = xs - x0f;
        int xi1 = xi0 + 1;
        float v0 = (xi0 >= 0 && xi0 < W_) ? 1.f : 0.f;
        float v1 = (xi1 >= 0 && xi1 < W_) ? 1.f : 0.f;
        int xc0 = min(max(xi0, 0), W_ - 1);
        int xc1 = min(max(xi1, 0), W_ - 1);
        const float* rrow = right + (size_t)(b * 3 + cc) * HW_ + (size_t)gy * W_;
        float warped = (1.f - w1) * v0 * rrow[xc0] + w1 * v1 * rrow[xc1];
        val = warped - left[(size_t)(b * 3 + cc) * HW_ + p];
      }
    }
    smem[c][yy][xx] = val;
  }
  __syncthreads();

  float acc[C_OUT];
#pragma unroll
  for (int j = 0; j < C_OUT; j++) acc[j] = 0.f;

  for (int c = 0; c < C_IN; c++) {
    float i00 = smem[c][ly + 0][lx + 0];
    float i01 = smem[c][ly + 0][lx + 1];
    float i02 = smem[c][ly + 0][lx + 2];
    float i10 = smem[c][ly + 1][lx + 0];
    float i11 = smem[c][ly + 1][lx + 1];
    float i12 = smem[c][ly + 1][lx + 2];
    float i20 = smem[c][ly + 2][lx + 0];
    float i21 = smem[c][ly + 2][lx + 1];
    float i22 = smem[c][ly + 2][lx + 2];
#pragma unroll
    for (int j = 0; j < C_OUT; j++) {
      const float* wp = wgt + ((size_t)j * C_IN + c) * 9;
      float a = acc[j];
      a = fmaf(i00, wp[0], a);
      a = fmaf(i01, wp[1], a);
      a = fmaf(i02, wp[2], a);
      a = fmaf(i10, wp[3], a);
      a = fmaf(i11, wp[4], a);
      a = fmaf(i12, wp[5], a);
      a = fmaf(i20, wp[6], a);
      a = fmaf(i21, wp[7], a);
      a = fmaf(i22, wp[8], a);
      acc[j] = a;
    }
  }

  const int oy = oy0 + ly;
  if (oy >= out_y0 + out_rows) return;
  const int ox = x0 + lx;
#pragma unroll
  for (int j = 0; j < C_OUT; j++) {
    float s = bn_g[j] * rsqrtf(bn_v[j] + 1e-5f);
    float r = acc[j] * s + (bn_b[j] - bn_m[j] * s);
    r = fmaxf(r, 0.f);
    out[((size_t)(gi * C_OUT + j) * out_rows + (oy - out_y0)) * W_ + ox] = r;
  }
}

// ---------------------------------------------------------------------------
// Generic banded 3x3 conv (band-buffer input), CO_TILE output channels per
// block, CHUNK input channels staged per LDS round.
// ---------------------------------------------------------------------------
template <int C_IN, int C_OUT, int CO_TILE, int CHUNK, bool BNRELU>
__global__ __launch_bounds__(256, 4) void conv3x3_band(
    const float* __restrict__ in, const float* __restrict__ wgt,
    const float* __restrict__ bn_g, const float* __restrict__ bn_b,
    const float* __restrict__ bn_m, const float* __restrict__ bn_v,
    float* __restrict__ out,
    int in_y0, int in_rows, int out_y0, int out_rows)
{
  constexpr int TX = 16, TY = 16;
  static_assert(C_IN % CHUNK == 0, "chunking");
  static_assert(C_OUT % CO_TILE == 0, "co tiling");
  constexpr int NCO = C_OUT / CO_TILE;
  constexpr int LH = TY + 2, LW = TX + 2, LWP = LW + 1;

  __shared__ float smem[CHUNK][LH][LWP];

  const int tilesX = W_ / TX;
  const int tilesY = (out_rows + TY - 1) / TY;
  int t = blockIdx.x;
  int txi = t % tilesX; t /= tilesX;
  int tyi = t % tilesY; t /= tilesY;
  int coi = t % NCO;
  int gi  = t / NCO;
  const int x0  = txi * TX;
  const int oy0 = out_y0 + tyi * TY;
  const int co0 = coi * CO_TILE;

  const int tid = threadIdx.x;
  const int lx = tid % TX;
  const int ly = tid / TX;

  float acc[CO_TILE];
#pragma unroll
  for (int j = 0; j < CO_TILE; j++) acc[j] = 0.f;

  for (int c0 = 0; c0 < C_IN; c0 += CHUNK) {
    for (int i = tid; i < CHUNK * LH * LW; i += 256) {
      int c = i / (LH * LW);
      int r = i % (LH * LW);
      int yy = r / LW;
      int xx = r % LW;
      int gy = oy0 + yy - 1;
      int gx = x0 + xx - 1;
      int by = gy - in_y0;
      float val = 0.f;
      if (gy >= 0 && gy < H_ && gx >= 0 && gx < W_ && by >= 0 && by < in_rows)
        val = in[((size_t)(gi * C_IN + c0 + c) * in_rows + by) * W_ + gx];
      smem[c][yy][xx] = val;
    }
    __syncthreads();

    for (int c = 0; c < CHUNK; c++) {
      float i00 = smem[c][ly + 0][lx + 0];
      float i01 = smem[c][ly + 0][lx + 1];
      float i02 = smem[c][ly + 0][lx + 2];
      float i10 = smem[c][ly + 1][lx + 0];
      float i11 = smem[c][ly + 1][lx + 1];
      float i12 = smem[c][ly + 1][lx + 2];
      float i20 = smem[c][ly + 2][lx + 0];
      float i21 = smem[c][ly + 2][lx + 1];
      float i22 = smem[c][ly + 2][lx + 2];
      const int ci = c0 + c;
#pragma unroll
      for (int j = 0; j < CO_TILE; j++) {
        const float* wp = wgt + ((size_t)(co0 + j) * C_IN + ci) * 9;
        float a = acc[j];
        a = fmaf(i00, wp[0], a);
        a = fmaf(i01, wp[1], a);
        a = fmaf(i02, wp[2], a);
        a = fmaf(i10, wp[3], a);
        a = fmaf(i11, wp[4], a);
        a = fmaf(i12, wp[5], a);
        a = fmaf(i20, wp[6], a);
        a = fmaf(i21, wp[7], a);
        a = fmaf(i22, wp[8], a);
        acc[j] = a;
      }
    }
    __syncthreads();
  }

  const int oy = oy0 + ly;
  if (oy >= out_y0 + out_rows) return;
  const int ox = x0 + lx;
#pragma unroll
  for (int j = 0; j < CO_TILE; j++) {
    float r = acc[j];
    const int co = co0 + j;
    if constexpr (BNRELU) {
      float s = bn_g[co] * rsqrtf(bn_v[co] + 1e-5f);
      r = r * s + (bn_b[co] - bn_m[co] * s);
      r = fmaxf(r, 0.f);
    }
    out[((size_t)(gi * C_OUT + co) * out_rows + (oy - out_y0)) * W_ + ox] = r;
  }
}

// ---------------------------------------------------------------------------
// Fused propagation epilogue over a band.
// oa layout (g, 24, rows, W): [o1(8)=dy, o2(8)=dx, aff_raw(8)]
// ---------------------------------------------------------------------------
__device__ __forceinline__ float bilin1(const float* __restrict__ img,
                                        float ys, float xs)
{
  float y0f = floorf(ys), x0f = floorf(xs);
  int y0 = (int)y0f, x0 = (int)x0f;
  float wy1 = ys - y0f, wx1 = xs - x0f;
  float wy0 = 1.f - wy1, wx0 = 1.f - wx1;
  int y1 = y0 + 1, x1 = x0 + 1;
  float vy0 = (y0 >= 0 && y0 < H_) ? 1.f : 0.f;
  float vy1 = (y1 >= 0 && y1 < H_) ? 1.f : 0.f;
  float vx0 = (x0 >= 0 && x0 < W_) ? 1.f : 0.f;
  float vx1 = (x1 >= 0 && x1 < W_) ? 1.f : 0.f;
  int yc0 = min(max(y0, 0), H_ - 1), yc1 = min(max(y1, 0), H_ - 1);
  int xc0 = min(max(x0, 0), W_ - 1), xc1 = min(max(x1, 0), W_ - 1);
  const float* r0 = img + (size_t)yc0 * W_;
  const float* r1 = img + (size_t)yc1 * W_;
  float v00 = r0[xc0], v01 = r0[xc1], v10 = r1[xc0], v11 = r1[xc1];
  return (wy0 * vy0) * ((wx0 * vx0) * v00 + (wx1 * vx1) * v01) +
         (wy1 * vy1) * ((wx0 * vx0) * v10 + (wx1 * vx1) * v11);
}

__global__ __launch_bounds__(256) void final_band(
    const float* __restrict__ oa, const float* __restrict__ conf,
    const float* __restrict__ disp, const float* __restrict__ asc,
    float* __restrict__ out, int b0, int g, int y0g, int rows)
{
  int idx = blockIdx.x * 256 + threadIdx.x;
  if (idx >= g * rows * W_) return;
  int x = idx % W_;
  int t = idx / W_;
  int yr = t % rows;
  int gi = t / rows;
  int y = y0g + yr;
  int b = b0 + gi;
  int p = y * W_ + x;

  const float scale = 1.f / (asc[0] + 1e-8f);
  const float* cimg = conf + (size_t)b * HW_;
  const float* dimg = disp + (size_t)b * HW_;
  const float* oab = oa + (size_t)gi * 24 * rows * W_;
  const size_t cs = (size_t)rows * W_;
  const size_t q = (size_t)yr * W_ + x;

  float offy[8], offx[8], a[8];
#pragma unroll
  for (int k = 0; k < 8; k++) {
    offy[k] = oab[(size_t)k * cs + q];
    offx[k] = oab[(size_t)(8 + k) * cs + q];
    float ar = oab[(size_t)(16 + k) * cs + q];
    float ca = bilin1(cimg, (float)y + offy[k], (float)x + offx[k]);
    a[k] = tanhf(ar) * scale * ca;
  }

  float s = 1e-4f;
#pragma unroll
  for (int k = 0; k < 8; k++) s += fabsf(a[k]);
  s = fmaxf(s, 1.f);
  float inv = 1.f / s;
  float suma = 0.f;
#pragma unroll
  for (int k = 0; k < 8; k++) { a[k] *= inv; suma += a[k]; }
  float aref = 1.f - suma;

  float inter = 0.f;
#pragma unroll
  for (int k9 = 0; k9 < 9; k9++) {
    float oy, ox, w;
    if (k9 < 4)       { oy = offy[k9];     ox = offx[k9];     w = a[k9]; }
    else if (k9 == 4) { oy = 0.f;          ox = 0.f;          w = aref;  }
    else              { oy = offy[k9 - 1]; ox = offx[k9 - 1]; w = a[k9 - 1]; }
    float ky = (float)(k9 / 3) - 1.f;
    float kx = (float)(k9 % 3) - 1.f;
    inter += w * bilin1(dimg, (float)y + ky + oy, (float)x + kx + ox);
  }
  inter = fmaxf(inter, 0.f);
  float cd = dimg[p];
  out[(size_t)b * HW_ + p] = fmaxf(0.7f * cd + 0.3f * inter, 0.f);
}

// ---------------------------------------------------------------------------
extern "C" void kernel_launch(void* const* d_in, const int* in_sizes, int n_in,
                              void* d_out, int out_size, void* d_ws, size_t ws_size,
                              hipStream_t stream)
{
  const float* disp   = (const float*)d_in[0];
  const float* normal = (const float*)d_in[1];
  const float* left   = (const float*)d_in[2];
  const float* right  = (const float*)d_in[3];
  const float* conf   = (const float*)d_in[4];
  const float* w1     = (const float*)d_in[5];
  const float* g1     = (const float*)d_in[6];
  const float* b1     = (const float*)d_in[7];
  const float* m1     = (const float*)d_in[8];
  const float* v1     = (const float*)d_in[9];
  const float* w2     = (const float*)d_in[10];
  const float* g2     = (const float*)d_in[11];
  const float* b2     = (const float*)d_in[12];
  const float* m2     = (const float*)d_in[13];
  const float* v2     = (const float*)d_in[14];
  const float* w3     = (const float*)d_in[15];
  const float* asc    = (const float*)d_in[16];
  float* out = (float*)d_out;

  // Band buffers: x1 (32ch, bh+4 rows), x2 (64ch, bh+2 rows).
  // oa (24ch, bh rows) aliases x1 (dead after conv2). Guidance is fused
  // into conv1 (no buffer).
  struct Cfg { int g, bh; };
  const Cfg cfgs[] = {{4, 384}, {4, 192}, {4, 96}, {4, 48}, {2, 48},
                      {1, 48}, {1, 24}, {1, 12}, {1, 8}, {1, 4}};
  int G = 1, BH = 4;
  for (const Cfg& c : cfgs) {
    size_t rows = (size_t)32 * (c.bh + 4) + (size_t)64 * (c.bh + 2);
    size_t need = (size_t)c.g * rows * W_ * sizeof(float);
    if (need <= ws_size) { G = c.g; BH = c.bh; break; }
  }

  float* ws = (float*)d_ws;
  float* x1_buf = ws;
  float* x2_buf = x1_buf + (size_t)G * 32 * (BH + 4) * W_;
  float* oa_buf = x1_buf;  // alias: x1 dead once conv3 runs

  const int tilesX = W_ / 16;  // 80

  for (int b0 = 0; b0 < B_; b0 += G) {
    for (int y0 = 0; y0 < H_; y0 += BH) {
      const int rows_out = min(BH, H_ - y0);
      const int y_x2_0 = max(y0 - 1, 0);
      const int y_x2_1 = min(y0 + rows_out + 1, H_);
      const int rows_x2 = y_x2_1 - y_x2_0;
      const int y_x1_0 = max(y0 - 2, 0);
      const int y_x1_1 = min(y0 + rows_out + 2, H_);
      const int rows_x1 = y_x1_1 - y_x1_0;

      {
        // guidance + 12 -> 32 conv + BN/ReLU, CO_TILE=32 (1 co-block)
        int grid = tilesX * ((rows_x1 + 15) / 16) * G;
        conv1_fused_band<<<grid, 256, 0, stream>>>(
            disp, normal, left, right, w1, g1, b1, m1, v1, x1_buf,
            b0, y_x1_0, rows_x1);
      }
      {
        // 32 -> 64, CO_TILE=32 (2 co-blocks), CHUNK=16
        int grid = tilesX * ((rows_x2 + 15) / 16) * 2 * G;
        conv3x3_band<32, 64, 32, 16, true><<<grid, 256, 0, stream>>>(
            x1_buf, w2, g2, b2, m2, v2, x2_buf,
            y_x1_0, rows_x1, y_x2_0, rows_x2);
      }
      {
        // 64 -> 24, CO_TILE=24 (1 co-block), CHUNK=16
        int grid = tilesX * ((rows_out + 15) / 16) * G;
        conv3x3_band<64, 24, 24, 16, false><<<grid, 256, 0, stream>>>(
            x2_buf, w3, nullptr, nullptr, nullptr, nullptr, oa_buf,
            y_x2_0, rows_x2, y0, rows_out);
      }
      {
        int n = G * rows_out * W_;
        final_band<<<(n + 255) / 256, 256, 0, stream>>>(
            oa_buf, conf, disp, asc, out, b0, G, y0, rows_out);
      }
    }
  }
}

// Round 5
// 3144.021 us; speedup vs baseline: 1.5542x; 1.5542x over previous
//
#include <hip/hip_runtime.h>
#include <math.h>

// Problem constants: B=4, H=384, W=1280, NUM=8, IDX_REF=4
static constexpr int B_ = 4;
static constexpr int H_ = 384;
static constexpr int W_ = 1280;
static constexpr int HW_ = H_ * W_;

// ---------------------------------------------------------------------------
// Guidance band = [normal(3), left(3), right(3), warp(right)-left(3)]
// layout (g, 12, rows, W) covering global rows [y0g, y0g+rows)
// ---------------------------------------------------------------------------
__global__ __launch_bounds__(256) void guidance_band(
    const float* __restrict__ disp, const float* __restrict__ normal,
    const float* __restrict__ left, const float* __restrict__ right,
    float* __restrict__ guid, int b0, int g, int y0g, int rows)
{
  int idx = blockIdx.x * 256 + threadIdx.x;
  if (idx >= g * rows * W_) return;
  int x = idx % W_;
  int t = idx / W_;
  int yr = t % rows;
  int gi = t / rows;
  int y = y0g + yr;
  int b = b0 + gi;
  int p = y * W_ + x;

  float d = disp[(size_t)b * HW_ + p];
  float xs = (float)x - d;
  float x0f = floorf(xs);
  int x0 = (int)x0f;
  float w1 = xs - x0f;
  int xi0 = x0, xi1 = x0 + 1;
  float v0 = (xi0 >= 0 && xi0 < W_) ? 1.f : 0.f;
  float v1 = (xi1 >= 0 && xi1 < W_) ? 1.f : 0.f;
  int xc0 = min(max(xi0, 0), W_ - 1);
  int xc1 = min(max(xi1, 0), W_ - 1);
  float w0f = (1.f - w1) * v0;
  float w1f = w1 * v1;

#pragma unroll
  for (int c = 0; c < 3; c++) {
    const float* rrow = right + (size_t)(b * 3 + c) * HW_ + (size_t)y * W_;
    float l = left[(size_t)(b * 3 + c) * HW_ + p];
    float n = normal[(size_t)(b * 3 + c) * HW_ + p];
    float r = rrow[x];
    float warped = w0f * rrow[xc0] + w1f * rrow[xc1];
    size_t base = ((size_t)gi * 12) * rows * W_ + (size_t)yr * W_ + x;
    size_t cs = (size_t)rows * W_;
    guid[base + (size_t)c * cs]       = n;
    guid[base + (size_t)(3 + c) * cs] = l;
    guid[base + (size_t)(6 + c) * cs] = r;
    guid[base + (size_t)(9 + c) * cs] = warped - l;
  }
}

// ---------------------------------------------------------------------------
// Banded 3x3 conv, pad=1 at true image borders, optional fused BN+ReLU.
// 32x16 output tile / 256 threads; each thread computes 2 adjacent pixels
// (cols 2*lx, 2*lx+1) for 8 output channels = 16 accumulators held as
// 16 NAMED float scalars (R4 lesson: float arrays of accumulators get
// parked in AGPRs -> v_accvgpr_read/write per FMA -> ~4x VALU bloat).
// Input channels staged in LDS CHUNK at a time (<=21 KB). Weights are
// wave-uniform scalar loads. Per-output accumulation order (ci ascending,
// 9 taps in fixed order) identical to prior rounds -> bit-identical.
// Grid: (W/32) * ceil(out_rows/16) * (C_OUT/8) * g.
// ---------------------------------------------------------------------------
#define CONV_CO(CO, AA, BB)                                                  \
  {                                                                          \
    const float* wp = wgt + ((size_t)(co0 + (CO)) * C_IN + ci) * 9;          \
    float w0 = wp[0], w1 = wp[1], w2 = wp[2], w3 = wp[3], w4 = wp[4];        \
    float w5 = wp[5], w6 = wp[6], w7 = wp[7], w8 = wp[8];                    \
    AA = fmaf(i00, w0, AA); AA = fmaf(i01, w1, AA); AA = fmaf(i02, w2, AA);  \
    AA = fmaf(i10, w3, AA); AA = fmaf(i11, w4, AA); AA = fmaf(i12, w5, AA);  \
    AA = fmaf(i20, w6, AA); AA = fmaf(i21, w7, AA); AA = fmaf(i22, w8, AA);  \
    BB = fmaf(i01, w0, BB); BB = fmaf(i02, w1, BB); BB = fmaf(i03, w2, BB);  \
    BB = fmaf(i11, w3, BB); BB = fmaf(i12, w4, BB); BB = fmaf(i13, w5, BB);  \
    BB = fmaf(i21, w6, BB); BB = fmaf(i22, w7, BB); BB = fmaf(i23, w8, BB);  \
  }

template <int C_IN, int C_OUT, int CHUNK, bool BNRELU>
__global__ __launch_bounds__(256, 4) void conv3x3_px2(
    const float* __restrict__ in, const float* __restrict__ wgt,
    const float* __restrict__ bn_g, const float* __restrict__ bn_b,
    const float* __restrict__ bn_m, const float* __restrict__ bn_v,
    float* __restrict__ out,
    int in_y0, int in_rows, int out_y0, int out_rows)
{
  constexpr int TX = 32, TY = 16;
  static_assert(C_IN % CHUNK == 0, "chunking");
  static_assert(C_OUT % 8 == 0, "co tiling");
  constexpr int NCO = C_OUT / 8;
  constexpr int LH = TY + 2;      // 18
  constexpr int LW = TX + 2;      // 34
  constexpr int LWS = 36;         // even stride, float2-aligned

  __shared__ float smem[CHUNK][LH][LWS];

  const int tilesX = W_ / TX;     // 40
  const int tilesY = (out_rows + TY - 1) / TY;
  int t = blockIdx.x;
  int txi = t % tilesX; t /= tilesX;
  int tyi = t % tilesY; t /= tilesY;
  int coi = t % NCO;
  int gi  = t / NCO;
  const int x0  = txi * TX;
  const int oy0 = out_y0 + tyi * TY;
  const int co0 = coi * 8;

  const int tid = threadIdx.x;
  const int lx = tid & 15;        // handles cols 2*lx, 2*lx+1
  const int ly = tid >> 4;        // 0..15

  float aA0 = 0.f, aA1 = 0.f, aA2 = 0.f, aA3 = 0.f;
  float aA4 = 0.f, aA5 = 0.f, aA6 = 0.f, aA7 = 0.f;
  float aB0 = 0.f, aB1 = 0.f, aB2 = 0.f, aB3 = 0.f;
  float aB4 = 0.f, aB5 = 0.f, aB6 = 0.f, aB7 = 0.f;

  for (int c0 = 0; c0 < C_IN; c0 += CHUNK) {
    for (int i = tid; i < CHUNK * LH * LW; i += 256) {
      int c = i / (LH * LW);
      int r = i % (LH * LW);
      int yy = r / LW;
      int xx = r % LW;
      int gy = oy0 + yy - 1;
      int gx = x0 + xx - 1;
      int by = gy - in_y0;
      float val = 0.f;
      if (gy >= 0 && gy < H_ && gx >= 0 && gx < W_ && by >= 0 && by < in_rows)
        val = in[((size_t)(gi * C_IN + c0 + c) * in_rows + by) * W_ + gx];
      smem[c][yy][xx] = val;
    }
    __syncthreads();

    for (int c = 0; c < CHUNK; c++) {
      const float* row0 = &smem[c][ly + 0][2 * lx];
      const float* row1 = &smem[c][ly + 1][2 * lx];
      const float* row2 = &smem[c][ly + 2][2 * lx];
      float2 q00 = *(const float2*)(row0);
      float2 q01 = *(const float2*)(row0 + 2);
      float2 q10 = *(const float2*)(row1);
      float2 q11 = *(const float2*)(row1 + 2);
      float2 q20 = *(const float2*)(row2);
      float2 q21 = *(const float2*)(row2 + 2);
      float i00 = q00.x, i01 = q00.y, i02 = q01.x, i03 = q01.y;
      float i10 = q10.x, i11 = q10.y, i12 = q11.x, i13 = q11.y;
      float i20 = q20.x, i21 = q20.y, i22 = q21.x, i23 = q21.y;
      const int ci = c0 + c;
      CONV_CO(0, aA0, aB0)
      CONV_CO(1, aA1, aB1)
      CONV_CO(2, aA2, aB2)
      CONV_CO(3, aA3, aB3)
      CONV_CO(4, aA4, aB4)
      CONV_CO(5, aA5, aB5)
      CONV_CO(6, aA6, aB6)
      CONV_CO(7, aA7, aB7)
    }
    __syncthreads();
  }

  const int oy = oy0 + ly;
  if (oy >= out_y0 + out_rows) return;
  const int ox = x0 + 2 * lx;

  float accA[8] = {aA0, aA1, aA2, aA3, aA4, aA5, aA6, aA7};
  float accB[8] = {aB0, aB1, aB2, aB3, aB4, aB5, aB6, aB7};
#pragma unroll
  for (int j = 0; j < 8; j++) {
    float rA = accA[j];
    float rB = accB[j];
    const int co = co0 + j;
    if constexpr (BNRELU) {
      float s = bn_g[co] * rsqrtf(bn_v[co] + 1e-5f);
      float o = bn_b[co] - bn_m[co] * s;
      rA = fmaxf(rA * s + o, 0.f);
      rB = fmaxf(rB * s + o, 0.f);
    }
    float2 v = {rA, rB};
    *(float2*)&out[((size_t)(gi * C_OUT + co) * out_rows + (oy - out_y0)) * W_ + ox] = v;
  }
}

// ---------------------------------------------------------------------------
// Fused propagation epilogue over a band.
// oa layout (g, 24, rows, W): [o1(8)=dy, o2(8)=dx, aff_raw(8)]
// ---------------------------------------------------------------------------
__device__ __forceinline__ float bilin1(const float* __restrict__ img,
                                        float ys, float xs)
{
  float y0f = floorf(ys), x0f = floorf(xs);
  int y0 = (int)y0f, x0 = (int)x0f;
  float wy1 = ys - y0f, wx1 = xs - x0f;
  float wy0 = 1.f - wy1, wx0 = 1.f - wx1;
  int y1 = y0 + 1, x1 = x0 + 1;
  float vy0 = (y0 >= 0 && y0 < H_) ? 1.f : 0.f;
  float vy1 = (y1 >= 0 && y1 < H_) ? 1.f : 0.f;
  float vx0 = (x0 >= 0 && x0 < W_) ? 1.f : 0.f;
  float vx1 = (x1 >= 0 && x1 < W_) ? 1.f : 0.f;
  int yc0 = min(max(y0, 0), H_ - 1), yc1 = min(max(y1, 0), H_ - 1);
  int xc0 = min(max(x0, 0), W_ - 1), xc1 = min(max(x1, 0), W_ - 1);
  const float* r0 = img + (size_t)yc0 * W_;
  const float* r1 = img + (size_t)yc1 * W_;
  float v00 = r0[xc0], v01 = r0[xc1], v10 = r1[xc0], v11 = r1[xc1];
  return (wy0 * vy0) * ((wx0 * vx0) * v00 + (wx1 * vx1) * v01) +
         (wy1 * vy1) * ((wx0 * vx0) * v10 + (wx1 * vx1) * v11);
}

__global__ __launch_bounds__(256) void final_band(
    const float* __restrict__ oa, const float* __restrict__ conf,
    const float* __restrict__ disp, const float* __restrict__ asc,
    float* __restrict__ out, int b0, int g, int y0g, int rows)
{
  int idx = blockIdx.x * 256 + threadIdx.x;
  if (idx >= g * rows * W_) return;
  int x = idx % W_;
  int t = idx / W_;
  int yr = t % rows;
  int gi = t / rows;
  int y = y0g + yr;
  int b = b0 + gi;
  int p = y * W_ + x;

  const float scale = 1.f / (asc[0] + 1e-8f);
  const float* cimg = conf + (size_t)b * HW_;
  const float* dimg = disp + (size_t)b * HW_;
  const float* oab = oa + (size_t)gi * 24 * rows * W_;
  const size_t cs = (size_t)rows * W_;
  const size_t q = (size_t)yr * W_ + x;

  float offy[8], offx[8], a[8];
#pragma unroll
  for (int k = 0; k < 8; k++) {
    offy[k] = oab[(size_t)k * cs + q];
    offx[k] = oab[(size_t)(8 + k) * cs + q];
    float ar = oab[(size_t)(16 + k) * cs + q];
    float ca = bilin1(cimg, (float)y + offy[k], (float)x + offx[k]);
    a[k] = tanhf(ar) * scale * ca;
  }

  float s = 1e-4f;
#pragma unroll
  for (int k = 0; k < 8; k++) s += fabsf(a[k]);
  s = fmaxf(s, 1.f);
  float inv = 1.f / s;
  float suma = 0.f;
#pragma unroll
  for (int k = 0; k < 8; k++) { a[k] *= inv; suma += a[k]; }
  float aref = 1.f - suma;

  float inter = 0.f;
#pragma unroll
  for (int k9 = 0; k9 < 9; k9++) {
    float oy, ox, w;
    if (k9 < 4)       { oy = offy[k9];     ox = offx[k9];     w = a[k9]; }
    else if (k9 == 4) { oy = 0.f;          ox = 0.f;          w = aref;  }
    else              { oy = offy[k9 - 1]; ox = offx[k9 - 1]; w = a[k9 - 1]; }
    float ky = (float)(k9 / 3) - 1.f;
    float kx = (float)(k9 % 3) - 1.f;
    inter += w * bilin1(dimg, (float)y + ky + oy, (float)x + kx + ox);
  }
  inter = fmaxf(inter, 0.f);
  float cd = dimg[p];
  out[(size_t)b * HW_ + p] = fmaxf(0.7f * cd + 0.3f * inter, 0.f);
}

// ---------------------------------------------------------------------------
extern "C" void kernel_launch(void* const* d_in, const int* in_sizes, int n_in,
                              void* d_out, int out_size, void* d_ws, size_t ws_size,
                              hipStream_t stream)
{
  const float* disp   = (const float*)d_in[0];
  const float* normal = (const float*)d_in[1];
  const float* left   = (const float*)d_in[2];
  const float* right  = (const float*)d_in[3];
  const float* conf   = (const float*)d_in[4];
  const float* w1     = (const float*)d_in[5];
  const float* g1     = (const float*)d_in[6];
  const float* b1     = (const float*)d_in[7];
  const float* m1     = (const float*)d_in[8];
  const float* v1     = (const float*)d_in[9];
  const float* w2     = (const float*)d_in[10];
  const float* g2     = (const float*)d_in[11];
  const float* b2     = (const float*)d_in[12];
  const float* m2     = (const float*)d_in[13];
  const float* v2     = (const float*)d_in[14];
  const float* w3     = (const float*)d_in[15];
  const float* asc    = (const float*)d_in[16];
  float* out = (float*)d_out;

  // Band buffers: guid (12ch, bh+6), x1 (32ch, bh+4), x2 (64ch, bh+2).
  // oa (24ch, bh) aliases the ws start (guid+x1 dead by conv3).
  struct Cfg { int g, bh; };
  const Cfg cfgs[] = {{4, 384}, {4, 192}, {4, 128}, {4, 96}, {4, 64},
                      {4, 48}, {2, 48}, {1, 48}, {1, 24}, {1, 12},
                      {1, 8}, {1, 4}};
  int G = 1, BH = 4;
  for (const Cfg& c : cfgs) {
    size_t rows = (size_t)12 * (c.bh + 6) + (size_t)32 * (c.bh + 4) +
                  (size_t)64 * (c.bh + 2);
    size_t need = (size_t)c.g * rows * W_ * sizeof(float);
    if (need <= ws_size) { G = c.g; BH = c.bh; break; }
  }

  float* ws = (float*)d_ws;
  float* guid_buf = ws;
  float* x1_buf   = guid_buf + (size_t)G * 12 * (BH + 6) * W_;
  float* x2_buf   = x1_buf   + (size_t)G * 32 * (BH + 4) * W_;
  float* oa_buf   = ws;  // alias: guid+x1 dead once conv3 runs

  const int tilesX = W_ / 32;  // 40

  for (int b0 = 0; b0 < B_; b0 += G) {
    for (int y0 = 0; y0 < H_; y0 += BH) {
      const int rows_out = min(BH, H_ - y0);
      const int y_x2_0 = max(y0 - 1, 0);
      const int y_x2_1 = min(y0 + rows_out + 1, H_);
      const int rows_x2 = y_x2_1 - y_x2_0;
      const int y_x1_0 = max(y0 - 2, 0);
      const int y_x1_1 = min(y0 + rows_out + 2, H_);
      const int rows_x1 = y_x1_1 - y_x1_0;
      const int y_g_0 = max(y0 - 3, 0);
      const int y_g_1 = min(y0 + rows_out + 3, H_);
      const int rows_g = y_g_1 - y_g_0;

      {
        int n = G * rows_g * W_;
        guidance_band<<<(n + 255) / 256, 256, 0, stream>>>(
            disp, normal, left, right, guid_buf, b0, G, y_g_0, rows_g);
      }
      {
        // 12 -> 32: NCO=4 co-blocks, CHUNK=6
        int grid = tilesX * ((rows_x1 + 15) / 16) * 4 * G;
        conv3x3_px2<12, 32, 6, true><<<grid, 256, 0, stream>>>(
            guid_buf, w1, g1, b1, m1, v1, x1_buf,
            y_g_0, rows_g, y_x1_0, rows_x1);
      }
      {
        // 32 -> 64: NCO=8 co-blocks, CHUNK=8
        int grid = tilesX * ((rows_x2 + 15) / 16) * 8 * G;
        conv3x3_px2<32, 64, 8, true><<<grid, 256, 0, stream>>>(
            x1_buf, w2, g2, b2, m2, v2, x2_buf,
            y_x1_0, rows_x1, y_x2_0, rows_x2);
      }
      {
        // 64 -> 24: NCO=3 co-blocks, CHUNK=8
        int grid = tilesX * ((rows_out + 15) / 16) * 3 * G;
        conv3x3_px2<64, 24, 8, false><<<grid, 256, 0, stream>>>(
            x2_buf, w3, nullptr, nullptr, nullptr, nullptr, oa_buf,
            y_x2_0, rows_x2, y0, rows_out);
      }
      {
        int n = G * rows_out * W_;
        final_band<<<(n + 255) / 256, 256, 0, stream>>>(
            oa_buf, conf, disp, asc, out, b0, G, y0, rows_out);
      }
    }
  }
}

// Round 6
// 2447.565 us; speedup vs baseline: 1.9964x; 1.2846x over previous
//
#include <hip/hip_runtime.h>
#include <math.h>

// Problem constants: B=4, H=384, W=1280, NUM=8, IDX_REF=4
static constexpr int B_ = 4;
static constexpr int H_ = 384;
static constexpr int W_ = 1280;
static constexpr int HW_ = H_ * W_;

// ---------------------------------------------------------------------------
// Guidance band = [normal(3), left(3), right(3), warp(right)-left(3)]
// layout (g, 12, rows, W) covering global rows [y0g, y0g+rows)
// ---------------------------------------------------------------------------
__global__ __launch_bounds__(256) void guidance_band(
    const float* __restrict__ disp, const float* __restrict__ normal,
    const float* __restrict__ left, const float* __restrict__ right,
    float* __restrict__ guid, int b0, int g, int y0g, int rows)
{
  int idx = blockIdx.x * 256 + threadIdx.x;
  if (idx >= g * rows * W_) return;
  int x = idx % W_;
  int t = idx / W_;
  int yr = t % rows;
  int gi = t / rows;
  int y = y0g + yr;
  int b = b0 + gi;
  int p = y * W_ + x;

  float d = disp[(size_t)b * HW_ + p];
  float xs = (float)x - d;
  float x0f = floorf(xs);
  int x0 = (int)x0f;
  float w1 = xs - x0f;
  int xi0 = x0, xi1 = x0 + 1;
  float v0 = (xi0 >= 0 && xi0 < W_) ? 1.f : 0.f;
  float v1 = (xi1 >= 0 && xi1 < W_) ? 1.f : 0.f;
  int xc0 = min(max(xi0, 0), W_ - 1);
  int xc1 = min(max(xi1, 0), W_ - 1);
  float w0f = (1.f - w1) * v0;
  float w1f = w1 * v1;

#pragma unroll
  for (int c = 0; c < 3; c++) {
    const float* rrow = right + (size_t)(b * 3 + c) * HW_ + (size_t)y * W_;
    float l = left[(size_t)(b * 3 + c) * HW_ + p];
    float n = normal[(size_t)(b * 3 + c) * HW_ + p];
    float r = rrow[x];
    float warped = w0f * rrow[xc0] + w1f * rrow[xc1];
    size_t base = ((size_t)gi * 12) * rows * W_ + (size_t)yr * W_ + x;
    size_t cs = (size_t)rows * W_;
    guid[base + (size_t)c * cs]       = n;
    guid[base + (size_t)(3 + c) * cs] = l;
    guid[base + (size_t)(6 + c) * cs] = r;
    guid[base + (size_t)(9 + c) * cs] = warped - l;
  }
}

// ---------------------------------------------------------------------------
// Banded 3x3 conv. 32x16 output tile / 256 threads; each thread computes
// 2 adjacent pixels x CO_TILE output channels, accumulators as NAMED float
// scalars. Staging is quad-vectorized: one address computation per 4
// contiguous floats (R5 lesson: per-element div/mod staging math was ~86%
// of FMA issue). LDS col j maps gx = x0-1+j; quads at j=4q (16B aligned).
// Per-output accumulation order (ci ascending, 9 taps fixed) identical to
// prior rounds -> bit-identical numerics.
// Grid: (W/32) * ceil(out_rows/16) * (C_OUT/CO_TILE) * g.
// ---------------------------------------------------------------------------
#define CONV_CO(CO, AA, BB)                                                  \
  {                                                                          \
    const float* wp = wgt + ((size_t)(co0 + (CO)) * C_IN + ci) * 9;          \
    float w0 = wp[0], w1 = wp[1], w2 = wp[2], w3 = wp[3], w4 = wp[4];        \
    float w5 = wp[5], w6 = wp[6], w7 = wp[7], w8 = wp[8];                    \
    AA = fmaf(i00, w0, AA); AA = fmaf(i01, w1, AA); AA = fmaf(i02, w2, AA);  \
    AA = fmaf(i10, w3, AA); AA = fmaf(i11, w4, AA); AA = fmaf(i12, w5, AA);  \
    AA = fmaf(i20, w6, AA); AA = fmaf(i21, w7, AA); AA = fmaf(i22, w8, AA);  \
    BB = fmaf(i01, w0, BB); BB = fmaf(i02, w1, BB); BB = fmaf(i03, w2, BB);  \
    BB = fmaf(i11, w3, BB); BB = fmaf(i12, w4, BB); BB = fmaf(i13, w5, BB);  \
    BB = fmaf(i21, w6, BB); BB = fmaf(i22, w7, BB); BB = fmaf(i23, w8, BB);  \
  }

template <int C_IN, int C_OUT, int CO_TILE, int CHUNK, bool BNRELU>
__global__ __launch_bounds__(256, 4) void conv3x3_px2(
    const float* __restrict__ in, const float* __restrict__ wgt,
    const float* __restrict__ bn_g, const float* __restrict__ bn_b,
    const float* __restrict__ bn_m, const float* __restrict__ bn_v,
    float* __restrict__ out,
    int in_y0, int in_rows, int out_y0, int out_rows)
{
  constexpr int TX = 32, TY = 16;
  static_assert(C_IN % CHUNK == 0, "chunking");
  static_assert(C_OUT % CO_TILE == 0, "co tiling");
  static_assert(CO_TILE == 8 || CO_TILE == 16, "co tile");
  constexpr int NCO = C_OUT / CO_TILE;
  constexpr int LH = TY + 2;      // 18
  constexpr int LWS = 36;         // 34 used + 2 pad; quad (16B) aligned rows
  constexpr int QPC = LH * 9;     // 162 quads per channel tile

  __shared__ float smem[CHUNK][LH][LWS];

  const int tilesX = W_ / TX;     // 40
  const int tilesY = (out_rows + TY - 1) / TY;
  int t = blockIdx.x;
  int txi = t % tilesX; t /= tilesX;
  int tyi = t % tilesY; t /= tilesY;
  int coi = t % NCO;
  int gi  = t / NCO;
  const int x0  = txi * TX;
  const int oy0 = out_y0 + tyi * TY;
  const int co0 = coi * CO_TILE;

  const int tid = threadIdx.x;
  const int lx = tid & 15;        // cols 2*lx, 2*lx+1
  const int ly = tid >> 4;        // 0..15

  float aA0 = 0.f, aA1 = 0.f, aA2 = 0.f, aA3 = 0.f;
  float aA4 = 0.f, aA5 = 0.f, aA6 = 0.f, aA7 = 0.f;
  float aA8 = 0.f, aA9 = 0.f, aA10 = 0.f, aA11 = 0.f;
  float aA12 = 0.f, aA13 = 0.f, aA14 = 0.f, aA15 = 0.f;
  float aB0 = 0.f, aB1 = 0.f, aB2 = 0.f, aB3 = 0.f;
  float aB4 = 0.f, aB5 = 0.f, aB6 = 0.f, aB7 = 0.f;
  float aB8 = 0.f, aB9 = 0.f, aB10 = 0.f, aB11 = 0.f;
  float aB12 = 0.f, aB13 = 0.f, aB14 = 0.f, aB15 = 0.f;

  for (int c0 = 0; c0 < C_IN; c0 += CHUNK) {
    // ---- quad-vectorized staging: 4 floats per address computation ----
    for (int i = tid; i < CHUNK * QPC; i += 256) {
      int c  = i / QPC;
      int r  = i - c * QPC;
      int yy = r / 9;
      int q  = r - yy * 9;
      int gy = oy0 + yy - 1;
      int by = gy - in_y0;
      int gx = x0 + 4 * q - 1;    // LDS col j=4q maps gx = x0-1+4q
      float v0 = 0.f, v1 = 0.f, v2 = 0.f, v3 = 0.f;
      if ((unsigned)by < (unsigned)in_rows) {
        const float* src = in + ((size_t)(gi * C_IN + c0 + c) * in_rows + by) * W_;
        v0 = ((unsigned)(gx + 0) < (unsigned)W_) ? src[gx + 0] : 0.f;
        v1 = ((unsigned)(gx + 1) < (unsigned)W_) ? src[gx + 1] : 0.f;
        v2 = ((unsigned)(gx + 2) < (unsigned)W_) ? src[gx + 2] : 0.f;
        v3 = ((unsigned)(gx + 3) < (unsigned)W_) ? src[gx + 3] : 0.f;
      }
      float* dst = &smem[c][yy][4 * q];
      dst[0] = v0; dst[1] = v1; dst[2] = v2; dst[3] = v3;
    }
    __syncthreads();

    for (int c = 0; c < CHUNK; c++) {
      const float* row0 = &smem[c][ly + 0][2 * lx];
      const float* row1 = &smem[c][ly + 1][2 * lx];
      const float* row2 = &smem[c][ly + 2][2 * lx];
      float2 q00 = *(const float2*)(row0);
      float2 q01 = *(const float2*)(row0 + 2);
      float2 q10 = *(const float2*)(row1);
      float2 q11 = *(const float2*)(row1 + 2);
      float2 q20 = *(const float2*)(row2);
      float2 q21 = *(const float2*)(row2 + 2);
      float i00 = q00.x, i01 = q00.y, i02 = q01.x, i03 = q01.y;
      float i10 = q10.x, i11 = q10.y, i12 = q11.x, i13 = q11.y;
      float i20 = q20.x, i21 = q20.y, i22 = q21.x, i23 = q21.y;
      const int ci = c0 + c;
      CONV_CO(0, aA0, aB0)
      CONV_CO(1, aA1, aB1)
      CONV_CO(2, aA2, aB2)
      CONV_CO(3, aA3, aB3)
      CONV_CO(4, aA4, aB4)
      CONV_CO(5, aA5, aB5)
      CONV_CO(6, aA6, aB6)
      CONV_CO(7, aA7, aB7)
      if constexpr (CO_TILE == 16) {
        CONV_CO(8,  aA8,  aB8)
        CONV_CO(9,  aA9,  aB9)
        CONV_CO(10, aA10, aB10)
        CONV_CO(11, aA11, aB11)
        CONV_CO(12, aA12, aB12)
        CONV_CO(13, aA13, aB13)
        CONV_CO(14, aA14, aB14)
        CONV_CO(15, aA15, aB15)
      }
    }
    __syncthreads();
  }

  const int oy = oy0 + ly;
  if (oy >= out_y0 + out_rows) return;
  const int ox = x0 + 2 * lx;

  float accA[16] = {aA0, aA1, aA2,  aA3,  aA4,  aA5,  aA6,  aA7,
                    aA8, aA9, aA10, aA11, aA12, aA13, aA14, aA15};
  float accB[16] = {aB0, aB1, aB2,  aB3,  aB4,  aB5,  aB6,  aB7,
                    aB8, aB9, aB10, aB11, aB12, aB13, aB14, aB15};
#pragma unroll
  for (int j = 0; j < CO_TILE; j++) {
    float rA = accA[j];
    float rB = accB[j];
    const int co = co0 + j;
    if constexpr (BNRELU) {
      float s = bn_g[co] * rsqrtf(bn_v[co] + 1e-5f);
      float o = bn_b[co] - bn_m[co] * s;
      rA = fmaxf(rA * s + o, 0.f);
      rB = fmaxf(rB * s + o, 0.f);
    }
    float2 v = {rA, rB};
    *(float2*)&out[((size_t)(gi * C_OUT + co) * out_rows + (oy - out_y0)) * W_ + ox] = v;
  }
}

// ---------------------------------------------------------------------------
// Fused propagation epilogue over a band.
// oa layout (g, 24, rows, W): [o1(8)=dy, o2(8)=dx, aff_raw(8)]
// ---------------------------------------------------------------------------
__device__ __forceinline__ float bilin1(const float* __restrict__ img,
                                        float ys, float xs)
{
  float y0f = floorf(ys), x0f = floorf(xs);
  int y0 = (int)y0f, x0 = (int)x0f;
  float wy1 = ys - y0f, wx1 = xs - x0f;
  float wy0 = 1.f - wy1, wx0 = 1.f - wx1;
  int y1 = y0 + 1, x1 = x0 + 1;
  float vy0 = (y0 >= 0 && y0 < H_) ? 1.f : 0.f;
  float vy1 = (y1 >= 0 && y1 < H_) ? 1.f : 0.f;
  float vx0 = (x0 >= 0 && x0 < W_) ? 1.f : 0.f;
  float vx1 = (x1 >= 0 && x1 < W_) ? 1.f : 0.f;
  int yc0 = min(max(y0, 0), H_ - 1), yc1 = min(max(y1, 0), H_ - 1);
  int xc0 = min(max(x0, 0), W_ - 1), xc1 = min(max(x1, 0), W_ - 1);
  const float* r0 = img + (size_t)yc0 * W_;
  const float* r1 = img + (size_t)yc1 * W_;
  float v00 = r0[xc0], v01 = r0[xc1], v10 = r1[xc0], v11 = r1[xc1];
  return (wy0 * vy0) * ((wx0 * vx0) * v00 + (wx1 * vx1) * v01) +
         (wy1 * vy1) * ((wx0 * vx0) * v10 + (wx1 * vx1) * v11);
}

__global__ __launch_bounds__(256) void final_band(
    const float* __restrict__ oa, const float* __restrict__ conf,
    const float* __restrict__ disp, const float* __restrict__ asc,
    float* __restrict__ out, int b0, int g, int y0g, int rows)
{
  int idx = blockIdx.x * 256 + threadIdx.x;
  if (idx >= g * rows * W_) return;
  int x = idx % W_;
  int t = idx / W_;
  int yr = t % rows;
  int gi = t / rows;
  int y = y0g + yr;
  int b = b0 + gi;
  int p = y * W_ + x;

  const float scale = 1.f / (asc[0] + 1e-8f);
  const float* cimg = conf + (size_t)b * HW_;
  const float* dimg = disp + (size_t)b * HW_;
  const float* oab = oa + (size_t)gi * 24 * rows * W_;
  const size_t cs = (size_t)rows * W_;
  const size_t q = (size_t)yr * W_ + x;

  float offy[8], offx[8], a[8];
#pragma unroll
  for (int k = 0; k < 8; k++) {
    offy[k] = oab[(size_t)k * cs + q];
    offx[k] = oab[(size_t)(8 + k) * cs + q];
    float ar = oab[(size_t)(16 + k) * cs + q];
    float ca = bilin1(cimg, (float)y + offy[k], (float)x + offx[k]);
    a[k] = tanhf(ar) * scale * ca;
  }

  float s = 1e-4f;
#pragma unroll
  for (int k = 0; k < 8; k++) s += fabsf(a[k]);
  s = fmaxf(s, 1.f);
  float inv = 1.f / s;
  float suma = 0.f;
#pragma unroll
  for (int k = 0; k < 8; k++) { a[k] *= inv; suma += a[k]; }
  float aref = 1.f - suma;

  float inter = 0.f;
#pragma unroll
  for (int k9 = 0; k9 < 9; k9++) {
    float oy, ox, w;
    if (k9 < 4)       { oy = offy[k9];     ox = offx[k9];     w = a[k9]; }
    else if (k9 == 4) { oy = 0.f;          ox = 0.f;          w = aref;  }
    else              { oy = offy[k9 - 1]; ox = offx[k9 - 1]; w = a[k9 - 1]; }
    float ky = (float)(k9 / 3) - 1.f;
    float kx = (float)(k9 % 3) - 1.f;
    inter += w * bilin1(dimg, (float)y + ky + oy, (float)x + kx + ox);
  }
  inter = fmaxf(inter, 0.f);
  float cd = dimg[p];
  out[(size_t)b * HW_ + p] = fmaxf(0.7f * cd + 0.3f * inter, 0.f);
}

// ---------------------------------------------------------------------------
extern "C" void kernel_launch(void* const* d_in, const int* in_sizes, int n_in,
                              void* d_out, int out_size, void* d_ws, size_t ws_size,
                              hipStream_t stream)
{
  const float* disp   = (const float*)d_in[0];
  const float* normal = (const float*)d_in[1];
  const float* left   = (const float*)d_in[2];
  const float* right  = (const float*)d_in[3];
  const float* conf   = (const float*)d_in[4];
  const float* w1     = (const float*)d_in[5];
  const float* g1     = (const float*)d_in[6];
  const float* b1     = (const float*)d_in[7];
  const float* m1     = (const float*)d_in[8];
  const float* v1     = (const float*)d_in[9];
  const float* w2     = (const float*)d_in[10];
  const float* g2     = (const float*)d_in[11];
  const float* b2     = (const float*)d_in[12];
  const float* m2     = (const float*)d_in[13];
  const float* v2     = (const float*)d_in[14];
  const float* w3     = (const float*)d_in[15];
  const float* asc    = (const float*)d_in[16];
  float* out = (float*)d_out;

  // Band buffers: guid (12ch, bh+6), x1 (32ch, bh+4), x2 (64ch, bh+2).
  // oa (24ch, bh) aliases the ws start (guid+x1 dead by conv3).
  // Prefer full-height bands (bh=384: zero halo recompute); ws_size on this
  // harness is ~256 MiB -> {1,384} (214 MB) is the expected pick.
  struct Cfg { int g, bh; };
  const Cfg cfgs[] = {{4, 384}, {2, 384}, {1, 384}, {4, 96}, {2, 96},
                      {1, 96}, {1, 48}, {1, 24}, {1, 12}, {1, 8}, {1, 4}};
  int G = 1, BH = 4;
  for (const Cfg& c : cfgs) {
    size_t rows = (size_t)12 * (c.bh + 6) + (size_t)32 * (c.bh + 4) +
                  (size_t)64 * (c.bh + 2);
    size_t need = (size_t)c.g * rows * W_ * sizeof(float);
    if (need <= ws_size) { G = c.g; BH = c.bh; break; }
  }

  float* ws = (float*)d_ws;
  float* guid_buf = ws;
  float* x1_buf   = guid_buf + (size_t)G * 12 * (BH + 6) * W_;
  float* x2_buf   = x1_buf   + (size_t)G * 32 * (BH + 4) * W_;
  float* oa_buf   = ws;  // alias: guid+x1 dead once conv3 runs

  const int tilesX = W_ / 32;  // 40

  for (int b0 = 0; b0 < B_; b0 += G) {
    for (int y0 = 0; y0 < H_; y0 += BH) {
      const int rows_out = min(BH, H_ - y0);
      const int y_x2_0 = max(y0 - 1, 0);
      const int y_x2_1 = min(y0 + rows_out + 1, H_);
      const int rows_x2 = y_x2_1 - y_x2_0;
      const int y_x1_0 = max(y0 - 2, 0);
      const int y_x1_1 = min(y0 + rows_out + 2, H_);
      const int rows_x1 = y_x1_1 - y_x1_0;
      const int y_g_0 = max(y0 - 3, 0);
      const int y_g_1 = min(y0 + rows_out + 3, H_);
      const int rows_g = y_g_1 - y_g_0;

      {
        int n = G * rows_g * W_;
        guidance_band<<<(n + 255) / 256, 256, 0, stream>>>(
            disp, normal, left, right, guid_buf, b0, G, y_g_0, rows_g);
      }
      {
        // 12 -> 32: CO_TILE=16 (NCO=2), CHUNK=12 (single round)
        int grid = tilesX * ((rows_x1 + 15) / 16) * 2 * G;
        conv3x3_px2<12, 32, 16, 12, true><<<grid, 256, 0, stream>>>(
            guid_buf, w1, g1, b1, m1, v1, x1_buf,
            y_g_0, rows_g, y_x1_0, rows_x1);
      }
      {
        // 32 -> 64: CO_TILE=16 (NCO=4), CHUNK=8
        int grid = tilesX * ((rows_x2 + 15) / 16) * 4 * G;
        conv3x3_px2<32, 64, 16, 8, true><<<grid, 256, 0, stream>>>(
            x1_buf, w2, g2, b2, m2, v2, x2_buf,
            y_x1_0, rows_x1, y_x2_0, rows_x2);
      }
      {
        // 64 -> 24: CO_TILE=8 (NCO=3), CHUNK=8
        int grid = tilesX * ((rows_out + 15) / 16) * 3 * G;
        conv3x3_px2<64, 24, 8, 8, false><<<grid, 256, 0, stream>>>(
            x2_buf, w3, nullptr, nullptr, nullptr, nullptr, oa_buf,
            y_x2_0, rows_x2, y0, rows_out);
      }
      {
        int n = G * rows_out * W_;
        final_band<<<(n + 255) / 256, 256, 0, stream>>>(
            oa_buf, conf, disp, asc, out, b0, G, y0, rows_out);
      }
    }
  }
}